// Round 1
// baseline (1702.932 us; speedup 1.0000x reference)
//
#include <hip/hip_runtime.h>
#include <hip/hip_bf16.h>

// Problem constants
#define BB 16
#define CC 256
#define CH 128
#define HH 128
#define WW 128
#define HW (HH*WW)
#define KPOOL 11
#define PADP 5
#define EPS 1e-5f

// ---------------------------------------------------------------------------
// Kernel 1: edge = x - boxavg11(x), separable, zero-pad, /121 always.
// One block handles a 32-row band of one (b,c) image. Output bf16.
// ---------------------------------------------------------------------------
__global__ __launch_bounds__(256) void box_edge_kernel(
    const float* __restrict__ x, __hip_bfloat16* __restrict__ edge)
{
    constexpr int RB = 32;                 // rows per block
    int blk  = blockIdx.x;
    int band = blk & 3;                    // H/RB = 4 bands
    int bc   = blk >> 2;                   // b*C + c
    const float* img = x + (size_t)bc * HW;

    __shared__ float tile[RB + 2*PADP][WW];  // 42*128*4 = 21.5 KB
    __shared__ float vs[RB][WW];             // 16 KB

    int h0 = band * RB;

    // load rows [h0-5, h0+RB+5), zero outside image
    for (int idx = threadIdx.x; idx < (RB + 2*PADP) * WW; idx += blockDim.x) {
        int r = idx >> 7;          // /128
        int w = idx & 127;
        int h = h0 - PADP + r;
        tile[r][w] = (h >= 0 && h < HH) ? img[h * WW + w] : 0.f;
    }
    __syncthreads();

    // vertical 11-tap sums
    for (int idx = threadIdx.x; idx < RB * WW; idx += blockDim.x) {
        int r = idx >> 7;
        int w = idx & 127;
        float s = 0.f;
#pragma unroll
        for (int j = 0; j < KPOOL; ++j) s += tile[r + j][w];
        vs[r][w] = s;
    }
    __syncthreads();

    // horizontal 11-tap sums + edge
    for (int idx = threadIdx.x; idx < RB * WW; idx += blockDim.x) {
        int r = idx >> 7;
        int w = idx & 127;
        float s = 0.f;
#pragma unroll
        for (int dx = -PADP; dx <= PADP; ++dx) {
            int ww = w + dx;
            if (ww >= 0 && ww < WW) s += vs[r][ww];
        }
        float e = tile[r + PADP][w] - s * (1.f / (KPOOL * KPOOL));
        edge[(size_t)bc * HW + (size_t)(h0 + r) * WW + w] = __float2bfloat16(e);
    }
}

// ---------------------------------------------------------------------------
// Kernel 2: h = relu(BN1(w1 @ edge + b1)); edge bf16 in, h bf16 out.
// Tile: 64 positions x 128 out-channels per block. 256 threads:
//   lane-in-p = tid&63, o-group = tid>>6 (wave-uniform -> weights via s_load).
// ---------------------------------------------------------------------------
__global__ __launch_bounds__(256) void gemm1_kernel(
    const __hip_bfloat16* __restrict__ edge,
    const float* __restrict__ w1, const float* __restrict__ b1,
    const float* __restrict__ g1, const float* __restrict__ be1,
    const float* __restrict__ m1, const float* __restrict__ v1,
    __hip_bfloat16* __restrict__ hbuf)
{
    int t  = blockIdx.x;               // grid = B * (HW/64)
    int b  = t >> 8;                   // 256 p-tiles per batch
    int p0 = (t & 255) * 64;
    int pl = threadIdx.x & 63;
    int og = __builtin_amdgcn_readfirstlane(threadIdx.x >> 6);  // 0..3, wave-uniform

    __shared__ float et[16][64];       // 4 KB staged activations

    float acc[32];
#pragma unroll
    for (int i = 0; i < 32; ++i) acc[i] = 0.f;

    const __hip_bfloat16* E = edge + (size_t)b * CC * HW;

    for (int kb = 0; kb < CC; kb += 16) {
        __syncthreads();
        for (int idx = threadIdx.x; idx < 16 * 64; idx += 256) {
            int kr = idx >> 6;
            int pc = idx & 63;
            et[kr][pc] = __bfloat162float(E[(size_t)(kb + kr) * HW + p0 + pc]);
        }
        __syncthreads();
#pragma unroll
        for (int k = 0; k < 16; ++k) {
            float e = et[k][pl];
#pragma unroll
            for (int i = 0; i < 32; ++i) {
                acc[i] += w1[(size_t)(og * 32 + i) * CC + kb + k] * e;
            }
        }
    }

    size_t obase = (size_t)b * CH * HW + p0 + pl;
#pragma unroll
    for (int i = 0; i < 32; ++i) {
        int o = og * 32 + i;
        float sc = g1[o] * rsqrtf(v1[o] + EPS);
        float sh = be1[o] - m1[o] * sc;
        float hv = (acc[i] + b1[o]) * sc + sh;
        hv = fmaxf(hv, 0.f);
        hbuf[obase + (size_t)o * HW] = __float2bfloat16(hv);
    }
}

// ---------------------------------------------------------------------------
// Kernel 3: gate = sigmoid(BN2(w2 @ h + b2)); out = x * (1 + gate).
// Tile: 64 positions x 128 out-channels; 2 blocks cover the 256 out-channels.
// ---------------------------------------------------------------------------
__global__ __launch_bounds__(256) void gemm2_kernel(
    const __hip_bfloat16* __restrict__ hbuf, const float* __restrict__ x,
    const float* __restrict__ w2, const float* __restrict__ b2,
    const float* __restrict__ g2, const float* __restrict__ be2,
    const float* __restrict__ m2, const float* __restrict__ v2,
    float* __restrict__ out)
{
    int t  = blockIdx.x;               // grid = B * (HW/64) * 2
    int oh = t & 1;
    t >>= 1;
    int b  = t >> 8;
    int p0 = (t & 255) * 64;
    int pl = threadIdx.x & 63;
    int og = __builtin_amdgcn_readfirstlane(threadIdx.x >> 6);

    __shared__ float ht[16][64];

    float acc[32];
#pragma unroll
    for (int i = 0; i < 32; ++i) acc[i] = 0.f;

    const __hip_bfloat16* Hm = hbuf + (size_t)b * CH * HW;

    for (int kb = 0; kb < CH; kb += 16) {
        __syncthreads();
        for (int idx = threadIdx.x; idx < 16 * 64; idx += 256) {
            int kr = idx >> 6;
            int pc = idx & 63;
            ht[kr][pc] = __bfloat162float(Hm[(size_t)(kb + kr) * HW + p0 + pc]);
        }
        __syncthreads();
#pragma unroll
        for (int k = 0; k < 16; ++k) {
            float h = ht[k][pl];
#pragma unroll
            for (int i = 0; i < 32; ++i) {
                acc[i] += w2[(size_t)(oh * 128 + og * 32 + i) * CH + kb + k] * h;
            }
        }
    }

    size_t base = (size_t)b * CC * HW + p0 + pl;
#pragma unroll
    for (int i = 0; i < 32; ++i) {
        int o = oh * 128 + og * 32 + i;
        float sc = g2[o] * rsqrtf(v2[o] + EPS);
        float sh = be2[o] - m2[o] * sc;
        float z  = (acc[i] + b2[o]) * sc + sh;
        float g  = 1.f / (1.f + __expf(-z));
        size_t idx = base + (size_t)o * HW;
        out[idx] = x[idx] * (1.f + g);
    }
}

// ---------------------------------------------------------------------------
extern "C" void kernel_launch(void* const* d_in, const int* in_sizes, int n_in,
                              void* d_out, int out_size, void* d_ws, size_t ws_size,
                              hipStream_t stream) {
    const float* x   = (const float*)d_in[0];
    const float* w1  = (const float*)d_in[1];
    const float* b1  = (const float*)d_in[2];
    const float* g1  = (const float*)d_in[3];
    const float* be1 = (const float*)d_in[4];
    const float* m1  = (const float*)d_in[5];
    const float* v1  = (const float*)d_in[6];
    const float* w2  = (const float*)d_in[7];
    const float* b2  = (const float*)d_in[8];
    const float* g2  = (const float*)d_in[9];
    const float* be2 = (const float*)d_in[10];
    const float* m2  = (const float*)d_in[11];
    const float* v2  = (const float*)d_in[12];
    float* out = (float*)d_out;

    const size_t edge_bytes = (size_t)BB * CC * HW * sizeof(__hip_bfloat16); // 128 MiB
    const size_t h_bytes    = (size_t)BB * CH * HW * sizeof(__hip_bfloat16); //  64 MiB

    __hip_bfloat16* edge;
    __hip_bfloat16* hbuf;
    if (ws_size >= edge_bytes + h_bytes) {
        edge = (__hip_bfloat16*)d_ws;
        hbuf = (__hip_bfloat16*)((char*)d_ws + edge_bytes);
    } else {
        // fallback: stage edge in d_out (out is written only by the final kernel,
        // after edge is dead)
        edge = (__hip_bfloat16*)d_out;
        hbuf = (__hip_bfloat16*)d_ws;
    }

    // K1: box filter + edge
    box_edge_kernel<<<BB * CC * (HH / 32), 256, 0, stream>>>(x, edge);

    // K2: conv1 + BN + ReLU
    gemm1_kernel<<<BB * (HW / 64), 256, 0, stream>>>(edge, w1, b1, g1, be1, m1, v1, hbuf);

    // K3: conv2 + BN + sigmoid + gated residual
    gemm2_kernel<<<BB * (HW / 64) * 2, 256, 0, stream>>>(hbuf, x, w2, b2, g2, be2, m2, v2, out);
}